// Round 12
// baseline (212.893 us; speedup 1.0000x reference)
//
#include <hip/hip_runtime.h>

#define D 1024      // in_features
#define E 64        // num experts
#define TPB 256     // threads per block (4 waves)
#define TOKS 128    // tokens per block (32 per wave, 2 strips of 16)
#define HALFB 131072 // bytes of one staged W half (16 k-steps)

typedef __attribute__((ext_vector_type(8))) short bf16x8;
typedef __attribute__((ext_vector_type(8))) unsigned short u16x8;
typedef __attribute__((ext_vector_type(4))) float f32x4;
typedef __attribute__((ext_vector_type(4))) unsigned int u32x4;

__device__ __forceinline__ unsigned short bf16_rne(float f) {
    unsigned u = __builtin_bit_cast(unsigned, f);
    u += 0x7fffu + ((u >> 16) & 1u);
    return (unsigned short)(u >> 16);
}
__device__ __forceinline__ float bf16_to_f(unsigned short h) {
    unsigned u = ((unsigned)h) << 16;
    return __builtin_bit_cast(float, u);
}
__device__ __forceinline__ unsigned cvt_pk_bf16(float a, float b) {
    // dst[15:0]=bf16_rne(a), dst[31:16]=bf16_rne(b) — bit-identical to bf16_rne
    unsigned r;
    asm("v_cvt_pk_bf16_f32 %0, %1, %2" : "=v"(r) : "v"(a), "v"(b));
    return r;
}
__device__ __forceinline__ float lo_val(unsigned p) {
    return __builtin_bit_cast(float, p << 16);
}
__device__ __forceinline__ float hi_val(unsigned p) {
    return __builtin_bit_cast(float, p & 0xffff0000u);
}
__device__ __forceinline__ void gload16(const void* g, void* l) {
    __builtin_amdgcn_global_load_lds(
        (const __attribute__((address_space(1))) unsigned int*)g,
        (__attribute__((address_space(3))) unsigned int*)l, 16, 0, 0);
}

// Split 8 fp32 into bf16 hi (RNE) + bf16 lo (RNE of exact residual).
// Bitwise-identical values to the original verified split_hi_lo scheme.
__device__ __forceinline__ void split8_rne(f32x4 a, f32x4 b, bf16x8& hv, bf16x8& lv) {
    unsigned h0 = cvt_pk_bf16(a[0], a[1]);
    unsigned h1 = cvt_pk_bf16(a[2], a[3]);
    unsigned h2 = cvt_pk_bf16(b[0], b[1]);
    unsigned h3 = cvt_pk_bf16(b[2], b[3]);
    unsigned l0 = cvt_pk_bf16(a[0] - lo_val(h0), a[1] - hi_val(h0));
    unsigned l1 = cvt_pk_bf16(a[2] - lo_val(h1), a[3] - hi_val(h1));
    unsigned l2 = cvt_pk_bf16(b[0] - lo_val(h2), b[1] - hi_val(h2));
    unsigned l3 = cvt_pk_bf16(b[2] - lo_val(h3), b[3] - hi_val(h3));
    hv = __builtin_bit_cast(bf16x8, (u32x4){h0, h1, h2, h3});
    lv = __builtin_bit_cast(bf16x8, (u32x4){l0, l1, l2, l3});
}

// ---------------------------------------------------------------------------
// One-time prep (proven): W -> RNE hi/lo bf16 in MFMA B-fragment lane order.
// Record f = (ks*8 + nt*2 + hl): 64 lanes x 16B; lane (n,q) holds
// W[nt*16+n][ks*32 + q*8 + 0..7].  256 KB -> d_ws.
// ---------------------------------------------------------------------------
__global__ __launch_bounds__(256) void router_prep(
        const float* __restrict__ W, unsigned short* __restrict__ Ws) {
    int t = blockIdx.x * 256 + threadIdx.x;  // 0..8191
    int lane = t & 63;
    int nt = (t >> 6) & 3;
    int ks = t >> 8;
    int n = lane & 15, q = lane >> 4;
    const float* src = W + (size_t)(nt * 16 + n) * D + ks * 32 + q * 8;
    u16x8 hv, lv;
#pragma unroll
    for (int j = 0; j < 8; ++j) {
        float v = src[j];
        unsigned short h = bf16_rne(v);
        hv[j] = h;
        lv[j] = bf16_rne(v - bf16_to_f(h));
    }
    size_t base = ((size_t)(ks * 8 + nt * 2) * 64 + lane) * 8;
    *(u16x8*)(Ws + base)          = hv;      // hl = 0
    *(u16x8*)(Ws + base + 64 * 8) = lv;      // hl = 1
}

// Named-member register sets only (rule #20).
struct Aset { f32x4 s0, s1, s2, s3, s4, s5, s6, s7; };   // 2 ksteps x 2 strips
struct Acc  { f32x4 c0, c1, c2, c3, d0, d1, d2, d3; };   // strip0 / strip1

// ---------------------------------------------------------------------------
// Main: minimum-barrier design.  256 blocks (1/CU), 128 tokens each.  W is
// staged in TWO 128 KB halves (16 k-steps each) via global_load_lds; between
// stages the 16 k-steps run BARRIER-FREE with A-loads double-buffered in
// named register sets.  5 barriers total per block (vs 9-65 in all prior
// designs) — direct test of the measured ~3.8us-per-barrier-segment cost.
// Per-token numerics bit-identical to all passing rounds.
// ---------------------------------------------------------------------------
__global__ __launch_bounds__(TPB, 1) void router_main(
        const float* __restrict__ x, const unsigned short* __restrict__ Ws,
        const float* __restrict__ bias, float* __restrict__ out, int T) {
    __shared__ __align__(16) union SM {
        unsigned char w[HALFB];             // 128 KB staged W half
        float ls[TOKS][E + 1];              // epilogue logits (union reuse)
    } sm;
    __shared__ float sbias[E];

    const int tid  = threadIdx.x;
    const int lane = tid & 63;
    const int wid  = tid >> 6;
    const int n    = lane & 15;
    const int q    = lane >> 4;
    const int t0   = blockIdx.x * TOKS;

    if (tid < E) sbias[tid] = bias[tid];

    // strip row bases: wave wid owns tokens [wid*32, wid*32+32)
    const float* ar0 = x + (size_t)(t0 + wid * 32 + n) * D + q * 8;       // strip0
    const float* ar1 = ar0 + (size_t)16 * D;                              // strip1
    const u32x4* gws = (const u32x4*)Ws;
    const char* ldsp = (const char*)sm.w + lane * 16;

    Acc acc;
    acc.c0 = (f32x4){0.f,0.f,0.f,0.f}; acc.c1 = acc.c0; acc.c2 = acc.c0; acc.c3 = acc.c0;
    acc.d0 = acc.c0; acc.d1 = acc.c0; acc.d2 = acc.c0; acc.d3 = acc.c0;

#define GLOADHALF(h_) do {                                            \
        const u32x4* _g = gws + (size_t)(h_) * 8192 + tid;            \
        char* _lb = (char*)sm.w + wid * 1024;                         \
        _Pragma("unroll")                                             \
        for (int r = 0; r < 32; ++r)                                  \
            gload16(_g + r * 256, _lb + r * 4096);                    \
    } while (0)

#define MFMA __builtin_amdgcn_mfma_f32_16x16x32_bf16

    // One k-step for both strips; per-token MFMA order identical to r8.
#define COMPSTEP(ksl_, au_, av_, bu_, bv_) do {                       \
        bf16x8 ah, al, eh, el;                                        \
        split8_rne(au_, av_, ah, al);                                 \
        split8_rne(bu_, bv_, eh, el);                                 \
        const char* _p = ldsp + (ksl_) * 8192;                        \
        {                                                             \
            bf16x8 bh = *(const bf16x8*)(_p);                         \
            bf16x8 bl = *(const bf16x8*)(_p + 1024);                  \
            acc.c0 = MFMA(ah, bh, acc.c0, 0, 0, 0);                   \
            acc.c0 = MFMA(al, bh, acc.c0, 0, 0, 0);                   \
            acc.c0 = MFMA(ah, bl, acc.c0, 0, 0, 0);                   \
            acc.d0 = MFMA(eh, bh, acc.d0, 0, 0, 0);                   \
            acc.d0 = MFMA(el, bh, acc.d0, 0, 0, 0);                   \
            acc.d0 = MFMA(eh, bl, acc.d0, 0, 0, 0);                   \
        }                                                             \
        {                                                             \
            bf16x8 bh = *(const bf16x8*)(_p + 2048);                  \
            bf16x8 bl = *(const bf16x8*)(_p + 3072);                  \
            acc.c1 = MFMA(ah, bh, acc.c1, 0, 0, 0);                   \
            acc.c1 = MFMA(al, bh, acc.c1, 0, 0, 0);                   \
            acc.c1 = MFMA(ah, bl, acc.c1, 0, 0, 0);                   \
            acc.d1 = MFMA(eh, bh, acc.d1, 0, 0, 0);                   \
            acc.d1 = MFMA(el, bh, acc.d1, 0, 0, 0);                   \
            acc.d1 = MFMA(eh, bl, acc.d1, 0, 0, 0);                   \
        }                                                             \
        {                                                             \
            bf16x8 bh = *(const bf16x8*)(_p + 4096);                  \
            bf16x8 bl = *(const bf16x8*)(_p + 5120);                  \
            acc.c2 = MFMA(ah, bh, acc.c2, 0, 0, 0);                   \
            acc.c2 = MFMA(al, bh, acc.c2, 0, 0, 0);                   \
            acc.c2 = MFMA(ah, bl, acc.c2, 0, 0, 0);                   \
            acc.d2 = MFMA(eh, bh, acc.d2, 0, 0, 0);                   \
            acc.d2 = MFMA(el, bh, acc.d2, 0, 0, 0);                   \
            acc.d2 = MFMA(eh, bl, acc.d2, 0, 0, 0);                   \
        }                                                             \
        {                                                             \
            bf16x8 bh = *(const bf16x8*)(_p + 6144);                  \
            bf16x8 bl = *(const bf16x8*)(_p + 7168);                  \
            acc.c3 = MFMA(ah, bh, acc.c3, 0, 0, 0);                   \
            acc.c3 = MFMA(al, bh, acc.c3, 0, 0, 0);                   \
            acc.c3 = MFMA(ah, bl, acc.c3, 0, 0, 0);                   \
            acc.d3 = MFMA(eh, bh, acc.d3, 0, 0, 0);                   \
            acc.d3 = MFMA(el, bh, acc.d3, 0, 0, 0);                   \
            acc.d3 = MFMA(eh, bl, acc.d3, 0, 0, 0);                   \
        }                                                             \
    } while (0)

#define ISSUEA(S_, ks_) do {                                          \
        S_.s0 = *(const f32x4*)(ar0 + (ks_) * 32);                    \
        S_.s1 = *(const f32x4*)(ar0 + (ks_) * 32 + 4);                \
        S_.s2 = *(const f32x4*)(ar0 + (ks_) * 32 + 32);               \
        S_.s3 = *(const f32x4*)(ar0 + (ks_) * 32 + 36);               \
        S_.s4 = *(const f32x4*)(ar1 + (ks_) * 32);                    \
        S_.s5 = *(const f32x4*)(ar1 + (ks_) * 32 + 4);                \
        S_.s6 = *(const f32x4*)(ar1 + (ks_) * 32 + 32);               \
        S_.s7 = *(const f32x4*)(ar1 + (ks_) * 32 + 36);               \
    } while (0)

#define COMP2(ksl_, S_) do {                                          \
        COMPSTEP((ksl_),     S_.s0, S_.s1, S_.s4, S_.s5);             \
        COMPSTEP((ksl_) + 1, S_.s2, S_.s3, S_.s6, S_.s7);             \
    } while (0)

    Aset P, Q;

    // ---- stage half 0 + first A chunk; barrier #1 drains the 32 gloads ----
    GLOADHALF(0);
    ISSUEA(P, 0);
    __syncthreads();

    // ---- half 0: 16 k-steps, barrier-free, A double-buffered P/Q ----
    ISSUEA(Q, 2);  COMP2(0,  P);
    ISSUEA(P, 4);  COMP2(2,  Q);
    ISSUEA(Q, 6);  COMP2(4,  P);
    ISSUEA(P, 8);  COMP2(6,  Q);
    ISSUEA(Q, 10); COMP2(8,  P);
    ISSUEA(P, 12); COMP2(10, Q);
    ISSUEA(Q, 14); COMP2(12, P);
    ISSUEA(P, 16); COMP2(14, Q);     // prefetch crosses into half 1

    __syncthreads();                 // #2: all LDS reads of half 0 done
    GLOADHALF(1);
    __syncthreads();                 // #3: half 1 staged

    // ---- half 1 ----
    ISSUEA(Q, 18); COMP2(0,  P);
    ISSUEA(P, 20); COMP2(2,  Q);
    ISSUEA(Q, 22); COMP2(4,  P);
    ISSUEA(P, 24); COMP2(6,  Q);
    ISSUEA(Q, 26); COMP2(8,  P);
    ISSUEA(P, 28); COMP2(10, Q);
    ISSUEA(Q, 30); COMP2(12, P);
    COMP2(14, Q);

    __syncthreads();                 // #4: before ls union reuse

    // ---- epilogue: logits (+bias) into union'd LDS, softmax + top-2 ----
    {
        const int row = wid * 32 + q * 4;
#define STORE_C(cc_, dd_, nt_) do {                                   \
            int col = (nt_) * 16 + n;                                 \
            float bv = sbias[col];                                    \
            sm.ls[row + 0][col] = cc_[0] + bv;                        \
            sm.ls[row + 1][col] = cc_[1] + bv;                        \
            sm.ls[row + 2][col] = cc_[2] + bv;                        \
            sm.ls[row + 3][col] = cc_[3] + bv;                        \
            sm.ls[row + 16][col] = dd_[0] + bv;                       \
            sm.ls[row + 17][col] = dd_[1] + bv;                       \
            sm.ls[row + 18][col] = dd_[2] + bv;                       \
            sm.ls[row + 19][col] = dd_[3] + bv;                       \
        } while (0)
        STORE_C(acc.c0, acc.d0, 0); STORE_C(acc.c1, acc.d1, 1);
        STORE_C(acc.c2, acc.d2, 2); STORE_C(acc.c3, acc.d3, 3);
#undef STORE_C
    }
    __syncthreads();                 // #5

    if (tid < TOKS) {
        float m1 = -3.4e38f, m2 = -3.4e38f;
        int i1 = 0, i2 = 0;
        for (int e = 0; e < E; ++e) {
            float v = sm.ls[tid][e];
            if (v > m1) { m2 = m1; i2 = i1; m1 = v; i1 = e; }
            else if (v > m2) { m2 = v; i2 = e; }
        }
        float Z = 0.f;
        for (int e = 0; e < E; ++e) Z += __expf(sm.ls[tid][e] - m1);
        float inv = 1.f / Z;
        int gt = t0 + tid;
        out[(size_t)gt * 2]     = inv;                  // exp(m1-m1)/Z
        out[(size_t)gt * 2 + 1] = __expf(m2 - m1) * inv;
        float* oi = out + (size_t)T * 2;
        oi[(size_t)gt * 2]     = (float)i1;             // indices as floats
        oi[(size_t)gt * 2 + 1] = (float)i2;
    }
}

extern "C" void kernel_launch(void* const* d_in, const int* in_sizes, int n_in,
                              void* d_out, int out_size, void* d_ws, size_t ws_size,
                              hipStream_t stream) {
    const float* x = (const float*)d_in[0];
    const float* W = (const float*)d_in[1];
    const float* b = (const float*)d_in[2];
    float* out = (float*)d_out;
    unsigned short* Ws = (unsigned short*)d_ws;   // needs 256 KB
    int T = in_sizes[0] / D;                      // 32768 tokens
    hipLaunchKernelGGL(router_prep, dim3(32), dim3(256), 0, stream, W, Ws);
    hipLaunchKernelGGL(router_main, dim3(T / TOKS), dim3(TPB), 0, stream,
                       x, Ws, b, out, T);
}